// Round 9
// baseline (75.576 us; speedup 1.0000x reference)
//
#include <hip/hip_runtime.h>
#include <stdint.h>

#define N 8192
#define MAX_E (64 * N)          // 524288
#define NCOL1 9                 // 9x9 (x,y) columns, width 5.556 > 5 + eps
#define NZ 32                   // fine z cells, width 50/32 = 1.5625
#define NCELLSF (NCOL1 * NCOL1 * NZ)     // 2592 cells
#define CPT 11                  // cells per thread in the scatter scan (256*11 >= 2592)
#define RCAP 128                // per-row neighbor-list capacity (lambda~34)
#define SCALE (9.0f / 50.0f)
#define ZSCALE (32.0f / 50.0f)
#define ZMARGIN 5.01f           // window margin: excluded => true dz > 5.009 =>
                                // true d2 > 25.09 >> threshold + 7e-3 ref error
#define POISON 0xAAAAAAAAu      // harness poisons d_ws to 0xAA before EVERY launch
#define M_WAVES 4               // rows per mask block (1 row per wave)
#define E_BLOCKS 256            // emit blocks (32 rows each)
#define E_ROWS 32

// Exact replication of numpy f32: sum(pos*pos, -1) = ((x*x)+(y*y))+(z*z),
// each product rounded (no fma).
__device__ __forceinline__ float sq_exact(float x, float y, float z) {
    return __fadd_rn(__fadd_rn(__fmul_rn(x, x), __fmul_rn(y, y)), __fmul_rn(z, z));
}

// d2 = RN(sqsum - RN(2*dot)); bit-identical to the reference op sequence.
// dist<5 <=> d2 < 0x1.8ffffep+4f. sq_j recomputed (deterministic) so pj.w
// can carry the point index.
__device__ __forceinline__ bool edge_pred(float xi, float yi, float zi, float sqi,
                                          float px, float py, float pz) {
    float sqj = sq_exact(px, py, pz);
    float dot = __fmaf_rn(zi, pz, __fmaf_rn(yi, py, __fmul_rn(xi, px)));
    float d2  = __fmaf_rn(-2.0f, dot, __fadd_rn(sqi, sqj));
    return d2 < 0x1.8ffffep+4f;
}

__device__ __forceinline__ int cell_of(float v) {          // 9-grid (x,y)
    int c = (int)(__fmul_rn(v, SCALE));
    return c > 8 ? 8 : c;
}
__device__ __forceinline__ int zcell_of(float v) {         // 32-grid (z), clamped
    int c = (int)(__fmul_rn(v, ZSCALE));
    c = c < 0 ? 0 : c;
    return c > (NZ - 1) ? (NZ - 1) : c;
}
__device__ __forceinline__ int cellf_of(float x, float y, float z) {
    return (cell_of(x) * NCOL1 + cell_of(y)) * NZ + zcell_of(z);
}

// Pass A: count points per fine cell. 32 wide blocks; 8192 atomics over 2592
// poisoned counters (~3 deep). Consumers subtract POISON.
__global__ __launch_bounds__(256) void count_kernel(const float* __restrict__ posf,
                                                    unsigned* __restrict__ gcount) {
    const int i = blockIdx.x * 256 + threadIdx.x;   // grid = 32 blocks
    float x = posf[3 * i], y = posf[3 * i + 1], z = posf[3 * i + 2];
    atomicAdd(&gcount[cellf_of(x, y, z)], 1u);
}

// Pass B (fused scan+scatter, R5 pattern at fine granularity): each of the 32
// blocks redundantly loads the 2592 final counts (10KB, L2-hot) and
// exclusive-scans them (shfl wave-scan, CPT=11 cells/thread). Block 0
// publishes cbase[2593]. Slot = cb[cell] + (atomicAdd(cursor[cell]) - POISON);
// cursor is a second poisoned region. Compaction => a column's z-window is ONE
// contiguous range; all 8192 slots exactly written; index rides in colpts.w.
__global__ __launch_bounds__(256) void scatter_kernel(const float* __restrict__ posf,
                                                      const unsigned* __restrict__ gcount,
                                                      unsigned* __restrict__ cursor,
                                                      int* __restrict__ cbase_g,
                                                      float4* __restrict__ colpts) {
    __shared__ int cb[NCELLSF];
    __shared__ int wtot[4];
    const int tid  = threadIdx.x;
    const int wave = tid >> 6;
    const int lane = tid & 63;

    int cnt[CPT];
    int s = 0;
#pragma unroll
    for (int k = 0; k < CPT; k++) {
        const int idx = tid * CPT + k;
        cnt[k] = (idx < NCELLSF) ? (int)(gcount[idx] - POISON) : 0;
        s += cnt[k];
    }
    int x = s;                                  // inclusive shfl-scan in wave
#pragma unroll
    for (int o = 1; o < 64; o <<= 1) {
        int t = __shfl_up(x, o);
        if (lane >= o) x += t;
    }
    if (lane == 63) wtot[wave] = x;
    __syncthreads();
    int woff = 0;
#pragma unroll
    for (int w = 0; w < 3; w++) woff += (wave > w) ? wtot[w] : 0;
    int run = woff + x - s;                     // exclusive prefix over threads
#pragma unroll
    for (int k = 0; k < CPT; k++) {
        const int idx = tid * CPT + k;
        if (idx < NCELLSF) {
            cb[idx] = run;
            if (blockIdx.x == 0) cbase_g[idx] = run;
            run += cnt[k];
        }
    }
    if (blockIdx.x == 0 && tid == 255) cbase_g[NCELLSF] = woff + x;  // = N
    __syncthreads();

    const int i = blockIdx.x * 256 + tid;
    float px = posf[3 * i], py = posf[3 * i + 1], pz = posf[3 * i + 2];
    const int cell = cellf_of(px, py, pz);
    const int slot = cb[cell] + (int)(atomicAdd(&cursor[cell], 1u) - POISON);
    colpts[slot] = make_float4(px, py, pz, __int_as_float(i));
}

// Pass 1: one wave per row. Fine z-window [zi-5.01, zi+5.01] -> ~7-8 cells =
// ONE contiguous compacted range per neighbor column (~213 avg candidates vs
// 306 at NZ=3-coarse, and no per-candidate segment select). Builds the row
// bitmap in wave-private LDS (barrier-free), compacts it to a sorted u16 col
// list in stage[row*RCAP]; counts[row] = degree. Blanket -1 prefill of out[].
// NO fences (R8 lesson); stream order covers inter-kernel visibility.
__global__ __launch_bounds__(256) void mask_kernel(const float* __restrict__ posf,
                                                   const int* __restrict__ cbase,
                                                   const float4* __restrict__ colpts,
                                                   uint16_t* __restrict__ stage,
                                                   int* __restrict__ counts,
                                                   int* __restrict__ out) {
    __shared__ uint32_t lmask[M_WAVES][256];   // 1KB bitmap per wave/row
    const int tid  = threadIdx.x;
    const int wave = tid >> 6;
    const int lane = tid & 63;
    const int row  = blockIdx.x * M_WAVES + wave;

    // -1 prefill of the whole output (2*MAX_E ints == 2048*256 int2 exactly)
    int2 neg; neg.x = -1; neg.y = -1;
    ((int2*)out)[blockIdx.x * 256 + tid] = neg;

#pragma unroll
    for (int k = lane; k < 256; k += 64) lmask[wave][k] = 0;
    __builtin_amdgcn_wave_barrier();           // ordering only; no exec cost

    const float xi = posf[3 * row], yi = posf[3 * row + 1], zi = posf[3 * row + 2];
    const float sqi = sq_exact(xi, yi, zi);
    const int cx = cell_of(xi), cy = cell_of(yi);
    const int zlo = zcell_of(__fadd_rn(zi, -ZMARGIN));
    const int zhi = zcell_of(__fadd_rn(zi,  ZMARGIN));

    for (int dx = -1; dx <= 1; dx++) {
        const int nx = cx + dx;
        if ((unsigned)nx > 8u) continue;       // wave-uniform branch
        for (int dy = -1; dy <= 1; dy++) {
            const int ny = cy + dy;
            if ((unsigned)ny > 8u) continue;
            const int cw = (nx * NCOL1 + ny) * NZ;
            const int s0 = cbase[cw + zlo];
            const int e0 = cbase[cw + zhi + 1];
            for (int k = s0 + lane; k < e0; k += 64) {
                float4 pj = colpts[k];
                const int j = __float_as_int(pj.w);
                if (j != row && edge_pred(xi, yi, zi, sqi, pj.x, pj.y, pj.z))
                    atomicOr(&lmask[wave][j >> 5], 1u << (j & 31));
            }
        }
    }
    __builtin_amdgcn_wave_barrier();           // ordering only; no exec cost

    // readback: lane l holds words 4l..4l+3 = bit-chunks [128l, 128l+128)
    uint4 u = ((const uint4*)lmask[wave])[lane];
    uint64_t k0 = (uint64_t)u.x | ((uint64_t)u.y << 32);
    uint64_t k1 = (uint64_t)u.z | ((uint64_t)u.w << 32);
    const int pc = __popcll(k0) + __popcll(k1);
    int xs = pc;                               // inclusive wave scan
#pragma unroll
    for (int o = 1; o < 64; o <<= 1) {
        int t = __shfl_up(xs, o);
        if (lane >= o) xs += t;
    }
    if (lane == 63) counts[row] = xs;          // row degree
    int off = xs - pc;                         // this lane's start in the list

    // compact sorted col list (bit position = col => sorted for free)
    uint16_t* dst = stage + (size_t)row * RCAP;
    const int col0 = lane * 128;
    uint64_t m = k0;
    while (m) {
        int b = __ffsll((unsigned long long)m) - 1;
        m &= m - 1;
        if (off < RCAP) dst[off] = (uint16_t)(col0 + b);
        off++;
    }
    m = k1;
    while (m) {
        int b = __ffsll((unsigned long long)m) - 1;
        m &= m - 1;
        if (off < RCAP) dst[off] = (uint16_t)(col0 + 64 + b);
        off++;
    }
}

// Pass 2: block-redundant scan of counts (32KB, L2-hot, shfl wave-scans) for
// slot bases, then a coalesced copy of each row's u16 col list into the
// (row, col) output planes. No tail fill (prefill done in mask).
__global__ __launch_bounds__(256) void emit_kernel(const uint16_t* __restrict__ stage,
                                                   const int* __restrict__ counts,
                                                   int* __restrict__ out) {
    const int tid  = threadIdx.x;
    const int wave = tid >> 6;
    const int lane = tid & 63;
    const int row0 = blockIdx.x * E_ROWS;

    __shared__ int incl[256];
    __shared__ int wtot[4];
    __shared__ int excl32[32];

    // thread t sums rows [t*32, t*32+32)
    const int4* c4 = (const int4*)counts;
    int s = 0;
#pragma unroll
    for (int k = 0; k < 8; k++) {
        int4 v = c4[tid * 8 + k];
        s += v.x + v.y + v.z + v.w;
    }
    int x = s;                                 // inclusive shfl-scan within wave
#pragma unroll
    for (int o = 1; o < 64; o <<= 1) {
        int t = __shfl_up(x, o);
        if (lane >= o) x += t;
    }
    if (lane == 63) wtot[wave] = x;

    // wave 0, lanes 0..31: exclusive scan of this block's 32 row counts
    if (tid < 32) {
        int c = counts[row0 + tid];
        int y = c;
#pragma unroll
        for (int o = 1; o < 32; o <<= 1) {
            int t = __shfl_up(y, o, 32);
            if (tid >= o) y += t;
        }
        excl32[tid] = y - c;
    }
    __syncthreads();
    int woff = 0;
#pragma unroll
    for (int w = 0; w < 3; w++) woff += (wave > w) ? wtot[w] : 0;
    incl[tid] = woff + x;
    __syncthreads();
    const int base = (blockIdx.x > 0) ? incl[blockIdx.x - 1] : 0;

#pragma unroll
    for (int r = 0; r < 8; r++) {
        const int lr  = wave * 8 + r;          // 0..31
        const int row = row0 + lr;
        int c = counts[row];
        c = c > RCAP ? RCAP : c;
        const int slot = base + excl32[lr];
        const uint16_t* src = stage + (size_t)row * RCAP;
        for (int k = lane; k < c; k += 64) {
            const int sk = slot + k;
            if (sk < MAX_E) {
                out[sk] = row;
                out[MAX_E + sk] = (int)src[k];
            }
        }
    }
}

extern "C" void kernel_launch(void* const* d_in, const int* in_sizes, int n_in,
                              void* d_out, int out_size, void* d_ws, size_t ws_size,
                              hipStream_t stream) {
    const float* posf = (const float*)d_in[0];
    int* out = (int*)d_out;
    char* ws = (char*)d_ws;
    int*      counts = (int*)ws;                        // 32KB @ 0
    unsigned* gcount = (unsigned*)(ws + (64 << 10));    // 2592 u32 @ 64KB (poisoned)
    unsigned* cursor = (unsigned*)(ws + (80 << 10));    // 2592 u32 @ 80KB (poisoned)
    int*      cbase  = (int*)(ws + (96 << 10));         // 2593 ints @ 96KB
    float4*   colpts = (float4*)(ws + (128 << 10));     // 8192 float4 = 128KB @ 128KB
    uint16_t* stage  = (uint16_t*)(ws + (1 << 20));     // 8192*128 u16 = 2MB @ 1MB

    count_kernel<<<N / 256, 256, 0, stream>>>(posf, gcount);
    scatter_kernel<<<N / 256, 256, 0, stream>>>(posf, gcount, cursor, cbase, colpts);
    mask_kernel<<<N / M_WAVES, 256, 0, stream>>>(posf, cbase, colpts,
                                                 stage, counts, out);
    emit_kernel<<<E_BLOCKS, 256, 0, stream>>>(stage, counts, out);
}

// Round 10
// 75.477 us; speedup vs baseline: 1.0013x; 1.0013x over previous
//
#include <hip/hip_runtime.h>
#include <stdint.h>

#define N 8192
#define MAX_E (64 * N)          // 524288
#define NCOL1 9                 // 9x9x9 grid, width 50/9 = 5.556 > 5 + eps
#define NCELLS (NCOL1 * NCOL1 * NCOL1)   // 729 cells
#define CAP 40                  // cell capacity: lambda=11.2, P(any cell>40)~1e-12
#define RCAP 128                // per-row neighbor-list capacity (lambda~34)
#define SCALE (9.0f / 50.0f)
#define POISON 0xAAAAAAAAu      // harness poisons d_ws to 0xAA before EVERY launch
#define M_WAVES 4               // rows per mask block (1 row per wave)
#define E_BLOCKS 256            // emit blocks (32 rows each)
#define E_ROWS 32

// Exact replication of numpy f32: sum(pos*pos, -1) = ((x*x)+(y*y))+(z*z),
// each product rounded (no fma).
__device__ __forceinline__ float sq_exact(float x, float y, float z) {
    return __fadd_rn(__fadd_rn(__fmul_rn(x, x), __fmul_rn(y, y)), __fmul_rn(z, z));
}

// d2 = RN(sqsum - RN(2*dot)); 2*dot is exact so fma(-2,dot,sqsum) is bit-identical.
// dist<5 <=> d2 < 0x1.8ffffep+4f (largest f32 below 25 has correctly-rounded sqrt
// equal to exactly 5.0, so that value must be excluded).
// |computed d2 - true d^2| <= ~7e-3, so pairs whose cells differ by >=2 in ANY
// coordinate have computed d2 > 30.8 >> threshold -> provably non-edges; the
// 3x3x3 neighbor-cell filter is bit-exact. sq_j is recomputed here (same
// deterministic op sequence as bin side), freeing pj.w to carry the index.
__device__ __forceinline__ bool edge_pred(float xi, float yi, float zi, float sqi,
                                          float px, float py, float pz) {
    float sqj = sq_exact(px, py, pz);
    float dot = __fmaf_rn(zi, pz, __fmaf_rn(yi, py, __fmul_rn(xi, px)));
    float d2  = __fmaf_rn(-2.0f, dot, __fadd_rn(sqi, sqj));
    return d2 < 0x1.8ffffep+4f;
}

__device__ __forceinline__ int cell_of(float v) {
    int c = (int)(__fmul_rn(v, SCALE));
    return c > 8 ? 8 : c;       // v=49.99999 -> product can round to 9.0
}

__device__ __forceinline__ int cell3_of(float x, float y, float z) {
    return (cell_of(x) * NCOL1 + cell_of(y)) * NCOL1 + cell_of(z);
}

// Single-pass 3D binning (R8 structure, best measured: 74.7us): 32 wide
// blocks, slot from atomicAdd on the 0xAA-poisoned counter (documented
// harness contract). Cell c owns slots [c*CAP, c*CAP+cnt). Point index rides
// in colpts.w -> mask does ONE float4 load per candidate.
// R9 lesson: fine-z compaction (count+scan+scatter, -30% candidates) was a
// net REGRESSION (+0.9us) -- mask is latency-bound, not candidate-bound.
__global__ __launch_bounds__(256) void bin_kernel(const float* __restrict__ posf,
                                                  unsigned* __restrict__ gcount,
                                                  float4* __restrict__ colpts) {
    const int i = blockIdx.x * 256 + threadIdx.x;   // grid = 32 blocks
    float x = posf[3 * i], y = posf[3 * i + 1], z = posf[3 * i + 2];
    const int cell = cell3_of(x, y, z);
    unsigned p = atomicAdd(&gcount[cell], 1u) - POISON;
    if (p < CAP) {
        colpts[cell * CAP + p] = make_float4(x, y, z, __int_as_float(i));
    }
}

// Pass 1: one wave per row. NEW vs R8: all 27 z-window cell counts for the
// <=9 neighbor columns are prefetched up front into registers (one overlapped
// L2 load burst) instead of 9 serialized {3 loads -> gather} rounds -- removes
// ~9 exposed ~200cy L2 latencies per row. Gathers use the branchless
// 3-segment select over adjacent cells in the CAP layout. Builds the row
// bitmap in wave-private LDS (barrier-free), compacts to a sorted u16 col
// list in stage[row*RCAP]; counts[row] = degree. Blanket -1 prefill of out[].
// NO fences (R8 lesson); stream order covers inter-kernel visibility.
__global__ __launch_bounds__(256) void mask_kernel(const float* __restrict__ posf,
                                                   const unsigned* __restrict__ gcount,
                                                   const float4* __restrict__ colpts,
                                                   uint16_t* __restrict__ stage,
                                                   int* __restrict__ counts,
                                                   int* __restrict__ out) {
    __shared__ uint32_t lmask[M_WAVES][256];   // 1KB bitmap per wave/row
    const int tid  = threadIdx.x;
    const int wave = tid >> 6;
    const int lane = tid & 63;
    const int row  = blockIdx.x * M_WAVES + wave;

    // -1 prefill of the whole output (2*MAX_E ints == 2048*256 int2 exactly);
    // emit later overwrites [0, E) with edges.
    int2 neg; neg.x = -1; neg.y = -1;
    ((int2*)out)[blockIdx.x * 256 + tid] = neg;

#pragma unroll
    for (int k = lane; k < 256; k += 64) lmask[wave][k] = 0;
    __builtin_amdgcn_wave_barrier();           // ordering only; no exec cost

    const float xi = posf[3 * row], yi = posf[3 * row + 1], zi = posf[3 * row + 2];
    const float sqi = sq_exact(xi, yi, zi);
    const int cx = cell_of(xi), cy = cell_of(yi), cz = cell_of(zi);
    const int zlo = (cz > 0) ? cz - 1 : 0;
    const int zhi = (cz < 8) ? cz + 1 : 8;     // window is 2-3 cells
    const bool z3 = (zhi - zlo == 2);          // wave-uniform

    // Prefetch all 9 column descriptors (c0, l0, l1, l2) -> registers.
    // Invalid columns collapse to zero-length; loads are independent and
    // issue as one burst (compiler batches, single s_waitcnt).
    int c0a[9], l0a[9], l1a[9], l2a[9];
#pragma unroll
    for (int q = 0; q < 9; q++) {
        const int nx = cx + q / 3 - 1;
        const int ny = cy + q % 3 - 1;
        const bool v = ((unsigned)nx <= 8u) & ((unsigned)ny <= 8u);
        const int c0 = v ? ((nx * NCOL1 + ny) * NCOL1 + zlo) : 0;
        int l0 = (int)(gcount[c0] - POISON);
        int l1 = (int)(gcount[c0 + 1] - POISON);
        int l2 = z3 ? (int)(gcount[c0 + 2] - POISON) : 0;
        l0 = l0 > CAP ? CAP : l0;
        l1 = l1 > CAP ? CAP : l1;
        l2 = l2 > CAP ? CAP : l2;
        c0a[q] = c0;
        l0a[q] = v ? l0 : 0;
        l1a[q] = v ? l1 : 0;
        l2a[q] = v ? l2 : 0;
    }

#pragma unroll
    for (int q = 0; q < 9; q++) {
        const int l0 = l0a[q], t01 = l0a[q] + l1a[q];
        const int tot = t01 + l2a[q];
        const int c0 = c0a[q];
        for (int k = lane; k < tot; k += 64) {
            // branchless 3-segment select over adjacent cells
            const int cellk = c0 + (k >= l0) + (k >= t01);
            const int off = k - ((k >= l0) ? l0 : 0) - ((k >= t01) ? l1a[q] : 0);
            float4 pj = colpts[cellk * CAP + off];
            const int j = __float_as_int(pj.w);
            if (j != row && edge_pred(xi, yi, zi, sqi, pj.x, pj.y, pj.z))
                atomicOr(&lmask[wave][j >> 5], 1u << (j & 31));
        }
    }
    __builtin_amdgcn_wave_barrier();           // ordering only; no exec cost

    // readback: lane l holds words 4l..4l+3 = bit-chunks [128l, 128l+128)
    uint4 u = ((const uint4*)lmask[wave])[lane];
    uint64_t k0 = (uint64_t)u.x | ((uint64_t)u.y << 32);
    uint64_t k1 = (uint64_t)u.z | ((uint64_t)u.w << 32);
    const int pc = __popcll(k0) + __popcll(k1);
    int xs = pc;                               // inclusive wave scan
#pragma unroll
    for (int o = 1; o < 64; o <<= 1) {
        int t = __shfl_up(xs, o);
        if (lane >= o) xs += t;
    }
    if (lane == 63) counts[row] = xs;          // row degree
    int off = xs - pc;                         // this lane's start in the list

    // compact sorted col list (bit position = col => sorted for free)
    uint16_t* dst = stage + (size_t)row * RCAP;
    const int col0 = lane * 128;
    uint64_t m = k0;
    while (m) {
        int b = __ffsll((unsigned long long)m) - 1;
        m &= m - 1;
        if (off < RCAP) dst[off] = (uint16_t)(col0 + b);
        off++;
    }
    m = k1;
    while (m) {
        int b = __ffsll((unsigned long long)m) - 1;
        m &= m - 1;
        if (off < RCAP) dst[off] = (uint16_t)(col0 + 64 + b);
        off++;
    }
}

// Pass 2: block-redundant scan of counts (32KB, L2-hot, shfl wave-scans) for
// slot bases, then a coalesced copy of each row's u16 col list into the
// (row, col) output planes. No tail fill (prefill done in mask).
__global__ __launch_bounds__(256) void emit_kernel(const uint16_t* __restrict__ stage,
                                                   const int* __restrict__ counts,
                                                   int* __restrict__ out) {
    const int tid  = threadIdx.x;
    const int wave = tid >> 6;
    const int lane = tid & 63;
    const int row0 = blockIdx.x * E_ROWS;

    __shared__ int incl[256];
    __shared__ int wtot[4];
    __shared__ int excl32[32];

    // thread t sums rows [t*32, t*32+32)
    const int4* c4 = (const int4*)counts;
    int s = 0;
#pragma unroll
    for (int k = 0; k < 8; k++) {
        int4 v = c4[tid * 8 + k];
        s += v.x + v.y + v.z + v.w;
    }
    int x = s;                                 // inclusive shfl-scan within wave
#pragma unroll
    for (int o = 1; o < 64; o <<= 1) {
        int t = __shfl_up(x, o);
        if (lane >= o) x += t;
    }
    if (lane == 63) wtot[wave] = x;

    // wave 0, lanes 0..31: exclusive scan of this block's 32 row counts
    if (tid < 32) {
        int c = counts[row0 + tid];
        int y = c;
#pragma unroll
        for (int o = 1; o < 32; o <<= 1) {
            int t = __shfl_up(y, o, 32);
            if (tid >= o) y += t;
        }
        excl32[tid] = y - c;
    }
    __syncthreads();
    int woff = 0;
#pragma unroll
    for (int w = 0; w < 3; w++) woff += (wave > w) ? wtot[w] : 0;
    incl[tid] = woff + x;
    __syncthreads();
    const int base = (blockIdx.x > 0) ? incl[blockIdx.x - 1] : 0;

#pragma unroll
    for (int r = 0; r < 8; r++) {
        const int lr  = wave * 8 + r;          // 0..31
        const int row = row0 + lr;
        int c = counts[row];
        c = c > RCAP ? RCAP : c;
        const int slot = base + excl32[lr];
        const uint16_t* src = stage + (size_t)row * RCAP;
        for (int k = lane; k < c; k += 64) {
            const int sk = slot + k;
            if (sk < MAX_E) {
                out[sk] = row;
                out[MAX_E + sk] = (int)src[k];
            }
        }
    }
}

extern "C" void kernel_launch(void* const* d_in, const int* in_sizes, int n_in,
                              void* d_out, int out_size, void* d_ws, size_t ws_size,
                              hipStream_t stream) {
    const float* posf = (const float*)d_in[0];
    int* out = (int*)d_out;
    char* ws = (char*)d_ws;
    int*      counts = (int*)ws;                        // 32KB @ 0
    unsigned* gcount = (unsigned*)(ws + (64 << 10));    // 729 uints @ 64KB (poisoned)
    float4*   colpts = (float4*)(ws + (256 << 10));     // 729*40 float4 = 456KB @ 256KB
    uint16_t* stage  = (uint16_t*)(ws + (1 << 20));     // 8192*128 u16 = 2MB @ 1MB

    bin_kernel<<<N / 256, 256, 0, stream>>>(posf, gcount, colpts);
    mask_kernel<<<N / M_WAVES, 256, 0, stream>>>(posf, gcount, colpts,
                                                 stage, counts, out);
    emit_kernel<<<E_BLOCKS, 256, 0, stream>>>(stage, counts, out);
}

// Round 11
// 74.313 us; speedup vs baseline: 1.0170x; 1.0157x over previous
//
#include <hip/hip_runtime.h>
#include <stdint.h>

#define N 8192
#define MAX_E (64 * N)          // 524288
#define NCOL1 9                 // 9x9x9 grid, width 50/9 = 5.556 > 5 + eps
#define NCELLS (NCOL1 * NCOL1 * NCOL1)   // 729 cells
#define CAP 40                  // cell capacity: lambda=11.2, P(any cell>40)~1e-12
#define RCAP 128                // per-row neighbor-list capacity (lambda~34)
#define SCALE (9.0f / 50.0f)
#define POISON 0xAAAAAAAAu      // harness poisons d_ws to 0xAA before EVERY launch
#define M_WAVES 4               // rows per mask block (1 row per wave)
#define E_BLOCKS 256            // emit blocks (32 rows each)
#define E_ROWS 32

// Exact replication of numpy f32: sum(pos*pos, -1) = ((x*x)+(y*y))+(z*z),
// each product rounded (no fma).
__device__ __forceinline__ float sq_exact(float x, float y, float z) {
    return __fadd_rn(__fadd_rn(__fmul_rn(x, x), __fmul_rn(y, y)), __fmul_rn(z, z));
}

// d2 = RN(sqsum - RN(2*dot)); 2*dot is exact so fma(-2,dot,sqsum) is bit-identical.
// dist<5 <=> d2 < 0x1.8ffffep+4f (largest f32 below 25 has correctly-rounded sqrt
// equal to exactly 5.0, so that value must be excluded).
// |computed d2 - true d^2| <= ~7e-3, so pairs whose cells differ by >=2 in ANY
// coordinate have computed d2 > 30.8 >> threshold -> provably non-edges; the
// 3x3x3 neighbor-cell filter is bit-exact. sq_j is recomputed here (same
// deterministic op sequence as bin side), freeing pj.w to carry the index.
__device__ __forceinline__ bool edge_pred(float xi, float yi, float zi, float sqi,
                                          float px, float py, float pz) {
    float sqj = sq_exact(px, py, pz);
    float dot = __fmaf_rn(zi, pz, __fmaf_rn(yi, py, __fmul_rn(xi, px)));
    float d2  = __fmaf_rn(-2.0f, dot, __fadd_rn(sqi, sqj));
    return d2 < 0x1.8ffffep+4f;
}

__device__ __forceinline__ int cell_of(float v) {
    int c = (int)(__fmul_rn(v, SCALE));
    return c > 8 ? 8 : c;       // v=49.99999 -> product can round to 9.0
}

__device__ __forceinline__ int cell3_of(float x, float y, float z) {
    return (cell_of(x) * NCOL1 + cell_of(y)) * NCOL1 + cell_of(z);
}

// Single-pass 3D binning (R8 structure, best measured: 74.7us): 32 wide
// blocks, slot from atomicAdd on the 0xAA-poisoned counter (documented
// harness contract). Cell c owns slots [c*CAP, c*CAP+cnt). Point index rides
// in colpts.w -> mask does ONE float4 load per candidate.
// Probed and rejected: fine-z compaction (R9, -30% candidates: +0.9us),
// 27-count register prefetch (R10: +0.8us), count+scan+scatter (R4: +2us),
// single-block fusion (R2: +7us), cooperative mask+emit fusion (R6: abort).
__global__ __launch_bounds__(256) void bin_kernel(const float* __restrict__ posf,
                                                  unsigned* __restrict__ gcount,
                                                  float4* __restrict__ colpts) {
    const int i = blockIdx.x * 256 + threadIdx.x;   // grid = 32 blocks
    float x = posf[3 * i], y = posf[3 * i + 1], z = posf[3 * i + 2];
    const int cell = cell3_of(x, y, z);
    unsigned p = atomicAdd(&gcount[cell], 1u) - POISON;
    if (p < CAP) {
        colpts[cell * CAP + p] = make_float4(x, y, z, __int_as_float(i));
    }
}

// Pass 1: one wave per row. Gathers ~306 candidates from the 9 neighbor
// columns (z-window cells adjacent in the CAP layout; branchless 2-compare
// select), builds the row bitmap in wave-private LDS (barrier-free), then
// COMPACTS it in-kernel: wave-scan of per-lane popcounts -> sorted u16 col
// list written to stage[row*RCAP] (bit position = col => sorted for free).
// counts[row] = degree. Blanket -1 prefill of out[] (one int2/thread, hidden
// under gather latency) so emit needs no tail fill.
// NO fences (R8 lesson); inter-kernel visibility guaranteed by stream order.
__global__ __launch_bounds__(256) void mask_kernel(const float* __restrict__ posf,
                                                   const unsigned* __restrict__ gcount,
                                                   const float4* __restrict__ colpts,
                                                   uint16_t* __restrict__ stage,
                                                   int* __restrict__ counts,
                                                   int* __restrict__ out) {
    __shared__ uint32_t lmask[M_WAVES][256];   // 1KB bitmap per wave/row
    const int tid  = threadIdx.x;
    const int wave = tid >> 6;
    const int lane = tid & 63;
    const int row  = blockIdx.x * M_WAVES + wave;

    // -1 prefill of the whole output (2*MAX_E ints == 2048*256 int2 exactly);
    // emit later overwrites [0, E) with edges.
    int2 neg; neg.x = -1; neg.y = -1;
    ((int2*)out)[blockIdx.x * 256 + tid] = neg;

#pragma unroll
    for (int k = lane; k < 256; k += 64) lmask[wave][k] = 0;
    __builtin_amdgcn_wave_barrier();           // ordering only; no exec cost

    const float xi = posf[3 * row], yi = posf[3 * row + 1], zi = posf[3 * row + 2];
    const float sqi = sq_exact(xi, yi, zi);
    const int cx = cell_of(xi), cy = cell_of(yi), cz = cell_of(zi);
    const int zlo = (cz > 0) ? cz - 1 : 0;
    const int zhi = (cz < 8) ? cz + 1 : 8;     // window is always 2-3 cells

    for (int dx = -1; dx <= 1; dx++) {
        const int nx = cx + dx;
        if ((unsigned)nx > 8u) continue;       // wave-uniform branch
        for (int dy = -1; dy <= 1; dy++) {
            const int ny = cy + dy;
            if ((unsigned)ny > 8u) continue;
            const int c0 = (nx * NCOL1 + ny) * NCOL1 + zlo;
            int l0 = (int)(gcount[c0] - POISON);     l0 = l0 > CAP ? CAP : l0;
            int l1 = (int)(gcount[c0 + 1] - POISON); l1 = l1 > CAP ? CAP : l1;
            int l2 = 0;
            if (zhi - zlo == 2) {
                l2 = (int)(gcount[c0 + 2] - POISON); l2 = l2 > CAP ? CAP : l2;
            }
            const int t01 = l0 + l1;
            const int tot = t01 + l2;
            for (int k = lane; k < tot; k += 64) {
                // branchless 3-segment select over adjacent cells
                const int cellk = c0 + (k >= l0) + (k >= t01);
                const int off = k - ((k >= l0) ? l0 : 0) - ((k >= t01) ? l1 : 0);
                float4 pj = colpts[cellk * CAP + off];
                const int j = __float_as_int(pj.w);
                if (j != row && edge_pred(xi, yi, zi, sqi, pj.x, pj.y, pj.z))
                    atomicOr(&lmask[wave][j >> 5], 1u << (j & 31));
            }
        }
    }
    __builtin_amdgcn_wave_barrier();           // ordering only; no exec cost

    // readback: lane l holds words 4l..4l+3 = bit-chunks [128l, 128l+128)
    uint4 u = ((const uint4*)lmask[wave])[lane];
    uint64_t k0 = (uint64_t)u.x | ((uint64_t)u.y << 32);
    uint64_t k1 = (uint64_t)u.z | ((uint64_t)u.w << 32);
    const int pc = __popcll(k0) + __popcll(k1);
    int xs = pc;                               // inclusive wave scan
#pragma unroll
    for (int o = 1; o < 64; o <<= 1) {
        int t = __shfl_up(xs, o);
        if (lane >= o) xs += t;
    }
    if (lane == 63) counts[row] = xs;          // row degree
    int off = xs - pc;                         // this lane's start in the list

    // compact sorted col list (bit position = col => sorted for free)
    uint16_t* dst = stage + (size_t)row * RCAP;
    const int col0 = lane * 128;
    uint64_t m = k0;
    while (m) {
        int b = __ffsll((unsigned long long)m) - 1;
        m &= m - 1;
        if (off < RCAP) dst[off] = (uint16_t)(col0 + b);
        off++;
    }
    m = k1;
    while (m) {
        int b = __ffsll((unsigned long long)m) - 1;
        m &= m - 1;
        if (off < RCAP) dst[off] = (uint16_t)(col0 + 64 + b);
        off++;
    }
}

// Pass 2: block-redundant scan of counts (32KB, L2-hot, shfl wave-scans) for
// slot bases, then a coalesced copy of each row's u16 col list into the
// (row, col) output planes. No tail fill (prefill done in mask).
__global__ __launch_bounds__(256) void emit_kernel(const uint16_t* __restrict__ stage,
                                                   const int* __restrict__ counts,
                                                   int* __restrict__ out) {
    const int tid  = threadIdx.x;
    const int wave = tid >> 6;
    const int lane = tid & 63;
    const int row0 = blockIdx.x * E_ROWS;

    __shared__ int incl[256];
    __shared__ int wtot[4];
    __shared__ int excl32[32];

    // thread t sums rows [t*32, t*32+32)
    const int4* c4 = (const int4*)counts;
    int s = 0;
#pragma unroll
    for (int k = 0; k < 8; k++) {
        int4 v = c4[tid * 8 + k];
        s += v.x + v.y + v.z + v.w;
    }
    int x = s;                                 // inclusive shfl-scan within wave
#pragma unroll
    for (int o = 1; o < 64; o <<= 1) {
        int t = __shfl_up(x, o);
        if (lane >= o) x += t;
    }
    if (lane == 63) wtot[wave] = x;

    // wave 0, lanes 0..31: exclusive scan of this block's 32 row counts
    if (tid < 32) {
        int c = counts[row0 + tid];
        int y = c;
#pragma unroll
        for (int o = 1; o < 32; o <<= 1) {
            int t = __shfl_up(y, o, 32);
            if (tid >= o) y += t;
        }
        excl32[tid] = y - c;
    }
    __syncthreads();
    int woff = 0;
#pragma unroll
    for (int w = 0; w < 3; w++) woff += (wave > w) ? wtot[w] : 0;
    incl[tid] = woff + x;
    __syncthreads();
    const int base = (blockIdx.x > 0) ? incl[blockIdx.x - 1] : 0;

#pragma unroll
    for (int r = 0; r < 8; r++) {
        const int lr  = wave * 8 + r;          // 0..31
        const int row = row0 + lr;
        int c = counts[row];
        c = c > RCAP ? RCAP : c;
        const int slot = base + excl32[lr];
        const uint16_t* src = stage + (size_t)row * RCAP;
        for (int k = lane; k < c; k += 64) {
            const int sk = slot + k;
            if (sk < MAX_E) {
                out[sk] = row;
                out[MAX_E + sk] = (int)src[k];
            }
        }
    }
}

extern "C" void kernel_launch(void* const* d_in, const int* in_sizes, int n_in,
                              void* d_out, int out_size, void* d_ws, size_t ws_size,
                              hipStream_t stream) {
    const float* posf = (const float*)d_in[0];
    int* out = (int*)d_out;
    char* ws = (char*)d_ws;
    int*      counts = (int*)ws;                        // 32KB @ 0
    unsigned* gcount = (unsigned*)(ws + (64 << 10));    // 729 uints @ 64KB (poisoned)
    float4*   colpts = (float4*)(ws + (256 << 10));     // 729*40 float4 = 456KB @ 256KB
    uint16_t* stage  = (uint16_t*)(ws + (1 << 20));     // 8192*128 u16 = 2MB @ 1MB

    bin_kernel<<<N / 256, 256, 0, stream>>>(posf, gcount, colpts);
    mask_kernel<<<N / M_WAVES, 256, 0, stream>>>(posf, gcount, colpts,
                                                 stage, counts, out);
    emit_kernel<<<E_BLOCKS, 256, 0, stream>>>(stage, counts, out);
}